// Round 3
// baseline (437.813 us; speedup 1.0000x reference)
//
#include <hip/hip_runtime.h>

// CostVolume — correctness-first baseline, fp32 in / fp32 out.
// out[n,d,y,x] = (1/64) * sum_c in1_pad[n,c, y+dy_d-4, x+dx_d-4] * in2[n,c,y,x]
// N=8 C=64 H=160 W=320; 53 (dy,dx) offsets of a 9x9 window (MD=4).
//
// Evidence from rounds 1-2: fp32-as-bf16 decode gave NaN (impossible for real
// bf16 data), bf16-as-fp32 readback stayed finite (impossible if storage were
// bf16) => storage is fp32 both ways; the bf16 threshold is grading-space only.
//
// One thread per output pixel (n,y,x), all 53 offsets in registers, loop over
// 64 channels, 9 guarded scalar loads per window row. No LDS, no double
// buffering, no wave specialization — every index trivially auditable.

#define HH 160
#define WW 320
#define CHN 64
#define ND 53

__global__ __launch_bounds__(256)
void cost_volume_simple(const float* __restrict__ in1,
                        const float* __restrict__ in2,
                        float* __restrict__ out) {
    const int g = blockIdx.x * 256 + threadIdx.x;
    const int x = g % WW;
    const int y = (g / WW) % HH;
    const int n = g / (WW * HH);

    float acc[ND];
    #pragma unroll
    for (int d = 0; d < ND; ++d) acc[d] = 0.f;

    const float* base1 = in1 + (size_t)n * CHN * HH * WW;
    const float* base2 = in2 + (size_t)n * CHN * HH * WW;

    for (int c = 0; c < CHN; ++c) {
        const float v2 = base2[(size_t)c * HH * WW + y * WW + x];
        const float* pl = base1 + (size_t)c * HH * WW;

        float f[9];
        // f[j] = in1[n,c, y+DY-4, x+j-4] with zero padding outside [0,H)x[0,W)
        #define ROWLOAD(DY) { \
            const int yy = y + (DY) - 4; \
            const bool rowok = (yy >= 0) && (yy < HH); \
            const float* rp = pl + yy * WW + (x - 4); \
            _Pragma("unroll") \
            for (int j = 0; j < 9; ++j) { \
                const int xx = x + j - 4; \
                f[j] = (rowok && (xx >= 0) && (xx < WW)) ? rp[j] : 0.f; \
            } }
        // out index D accumulates in1[.., x + J - 4] * in2[.., x]
        #define ACC(D, J) acc[D] = fmaf(f[J], v2, acc[D]);

        // INDEX -> (dy = idx/9, dx = idx%9), d in listed order:
        ROWLOAD(0) ACC(0,0)  ACC(1,2)  ACC(2,4)  ACC(3,6)  ACC(4,8)     // dy0 dx 0,2,4,6,8
        ROWLOAD(1) ACC(5,1)  ACC(6,3)  ACC(7,5)  ACC(8,7)               // dy1 dx 1,3,5,7
        ROWLOAD(2) ACC(9,0)  ACC(10,2) ACC(11,3) ACC(12,4) ACC(13,5) ACC(14,6) ACC(15,8)
        ROWLOAD(3) ACC(16,1) ACC(17,2) ACC(18,3) ACC(19,4) ACC(20,5) ACC(21,6) ACC(22,7)
        ROWLOAD(4) ACC(23,0) ACC(24,2) ACC(25,3) ACC(26,4) ACC(27,5) ACC(28,6) ACC(29,8)
        ROWLOAD(5) ACC(30,1) ACC(31,2) ACC(32,3) ACC(33,4) ACC(34,5) ACC(35,6) ACC(36,7)
        ROWLOAD(6) ACC(37,0) ACC(38,2) ACC(39,3) ACC(40,4) ACC(41,5) ACC(42,6) ACC(43,8)
        ROWLOAD(7) ACC(44,1) ACC(45,3) ACC(46,5) ACC(47,7)              // dy7 dx 1,3,5,7
        ROWLOAD(8) ACC(48,0) ACC(49,2) ACC(50,4) ACC(51,6) ACC(52,8)    // dy8 dx 0,2,4,6,8
        #undef ROWLOAD
        #undef ACC
    }

    const float s = 1.0f / 64.0f;
    const size_t ob = (size_t)n * ND * HH * WW + (size_t)y * WW + x;
    #pragma unroll
    for (int d = 0; d < ND; ++d)
        out[ob + (size_t)d * HH * WW] = acc[d] * s;
}

extern "C" void kernel_launch(void* const* d_in, const int* in_sizes, int n_in,
                              void* d_out, int out_size, void* d_ws, size_t ws_size,
                              hipStream_t stream) {
    const float* in1 = (const float*)d_in[0];
    const float* in2 = (const float*)d_in[1];
    float* out = (float*)d_out;

    const int total = 8 * HH * WW;            // 409600 threads, one per (n,y,x)
    dim3 grid(total / 256);                   // 1600 blocks
    dim3 block(256);
    cost_volume_simple<<<grid, block, 0, stream>>>(in1, in2, out);
}